// Round 15
// baseline (353.516 us; speedup 1.0000x reference)
//
#include <hip/hip_runtime.h>

// LinearAttention: B=2, L=2048, D=1024, H=16, FD=16, HD=64. fp32 in/out.
// Denominator chain (q,k proj + cumsum + dots) stays fp64 (cancellation,
// z amplifies ~3e4). v-proj/out-proj: bf16x3 MFMA GEMMs (A3=[Ahi|Alo|Ahi],
// B3=[Bhi|Bhi|Blo]).
// q,k proj R15: qk is LDS-READ-BW-bound (R12-R14 forensics: 512 KB/tile/CU
// = 4096 cyc > 2048 FMA cyc; VALUBusy pinned ~46% regardless of occupancy).
// Fix: 8x4 register tile (3 B/FMA) via 128-thread blocks, 2 waves, same
// 64x64x16 tile + f64 LDS + conflict-free reads (A 4-addr bcast, B 2-way).
// Bit-identical output. Lessons: no divergent-body fusion (R8); no split-K
// atomics (R9); audit banks on mapping change (R11); per-tile compute
// density rules (R13); occupancy beyond 2 blocks/CU buys nothing here (R9).

#define L_    2048
#define NROW  4096   // B*L
#define CHUNK 128
#define NCH   16
#define NBH   32
#define K3    3072

typedef __attribute__((ext_vector_type(8))) short short8v;
typedef __attribute__((ext_vector_type(4))) float floatx4;

__device__ __forceinline__ ushort bf_rne(float x) {
    unsigned u = __float_as_uint(x);
    return (ushort)((u + 0x7fffu + ((u >> 16) & 1u)) >> 16);
}
__device__ __forceinline__ float bf_to_f(ushort h) {
    return __uint_as_float(((unsigned)h) << 16);
}
__device__ __forceinline__ void gload16(const ushort* g, ushort* l) {
    __builtin_amdgcn_global_load_lds(
        (const __attribute__((address_space(1))) unsigned int*)g,
        (__attribute__((address_space(3))) unsigned int*)l, 16, 0, 0);
}

// ---- split fp32 [rows][1024] -> bf16 [rows][3072]: hi at 0 and hi2_off,
// ---- lo at lo_off.  A-style: lo_off=1024,hi2=2048. B-style: lo_off=2048,hi2=1024.
__global__ __launch_bounds__(256) void split3(const float* __restrict__ in,
                                              ushort* __restrict__ out3, int nrow,
                                              int lo_off, int hi2_off) {
    int idx = blockIdx.x * 256 + threadIdx.x;
    int row = idx >> 7, g = idx & 127;
    if (row >= nrow) return;
    const float* p = in + (size_t)row * 1024 + g * 8;
    float4 x0 = *(const float4*)p, x1 = *(const float4*)(p + 4);
    float xs[8] = {x0.x, x0.y, x0.z, x0.w, x1.x, x1.y, x1.z, x1.w};
    ushort hs[8], ls[8];
#pragma unroll
    for (int j = 0; j < 8; ++j) {
        ushort h = bf_rne(xs[j]);
        hs[j] = h;
        ls[j] = bf_rne(xs[j] - bf_to_f(h));
    }
    ushort* o = out3 + (size_t)row * 3072 + g * 8;
    ushort4 h0 = make_ushort4(hs[0], hs[1], hs[2], hs[3]);
    ushort4 h1 = make_ushort4(hs[4], hs[5], hs[6], hs[7]);
    *(ushort4*)(o)               = h0;
    *(ushort4*)(o + 4)           = h1;
    *(ushort4*)(o + hi2_off)     = h0;
    *(ushort4*)(o + hi2_off + 4) = h1;
    *(ushort4*)(o + lo_off)      = make_ushort4(ls[0], ls[1], ls[2], ls[3]);
    *(ushort4*)(o + lo_off + 4)  = make_ushort4(ls[4], ls[5], ls[6], ls[7]);
}

// -------- bf16 NT GEMM: C[M,1024] f32 = A3[M,3072] @ B3[1024,3072]^T --------
// Tile 128(M)x64(N), BK=64, 4 waves 2x2 (wave = 64x32), dbuf LDS 48KB ->
// 3 blocks/CU, gload_lds w=16, grid (16,32) = 512 blocks. (R10-proven)
__global__ __launch_bounds__(256) void gemm_bf16x3(const ushort* __restrict__ A3,
                                                   const ushort* __restrict__ B3,
                                                   float* __restrict__ Cm, int Nn) {
    __shared__ ushort As[2][8192];
    __shared__ ushort Bs[2][4096];
    const int tid = threadIdx.x;
    const int lane = tid & 63;
    const int wy = tid >> 7;
    const int wx = (tid >> 6) & 1;
    const int m0 = blockIdx.y * 128;
    const int n0 = blockIdx.x * 64;

    const int arow = tid >> 3;                   // 0..31
    const int aslot = (tid & 7) ^ (arow & 7);    // inverse-swizzled source slot
    const ushort* pA[4];
    const ushort* pB[2];
#pragma unroll
    for (int i = 0; i < 4; ++i)
        pA[i] = A3 + (size_t)(m0 + i * 32 + arow) * K3 + aslot * 8;
#pragma unroll
    for (int i = 0; i < 2; ++i)
        pB[i] = B3 + (size_t)(n0 + i * 32 + arow) * K3 + aslot * 8;

#define STAGE(buf, kk)                                              \
    do {                                                            \
        _Pragma("unroll") for (int i = 0; i < 4; ++i)               \
            gload16(pA[i] + (kk), &As[buf][i * 2048 + tid * 8]);    \
        _Pragma("unroll") for (int i = 0; i < 2; ++i)               \
            gload16(pB[i] + (kk), &Bs[buf][i * 2048 + tid * 8]);    \
    } while (0)

    const int abase = (wy * 64 + (lane & 15)) * 64;
    const int bbase = (wx * 32 + (lane & 15)) * 64;

    floatx4 acc[4][2] = {};
    STAGE(0, 0);
    for (int t = 0; t < 48; ++t) {
        const int cur = t & 1;
        __syncthreads();
        if (t < 47) STAGE(1 - cur, (t + 1) * 64);
#pragma unroll
        for (int ksub = 0; ksub < 2; ++ksub) {
            const int so = ((((lane >> 4) | (ksub << 2)) ^ (lane & 7)) << 3);
            short8v a[4], b[2];
#pragma unroll
            for (int mf = 0; mf < 4; ++mf)
                a[mf] = *(const short8v*)&As[cur][abase + mf * 1024 + so];
#pragma unroll
            for (int nf = 0; nf < 2; ++nf)
                b[nf] = *(const short8v*)&Bs[cur][bbase + nf * 1024 + so];
#pragma unroll
            for (int mf = 0; mf < 4; ++mf)
#pragma unroll
                for (int nf = 0; nf < 2; ++nf)
                    acc[mf][nf] = __builtin_amdgcn_mfma_f32_16x16x32_bf16(
                        a[mf], b[nf], acc[mf][nf], 0, 0, 0);
        }
    }
#undef STAGE

#pragma unroll
    for (int mf = 0; mf < 4; ++mf) {
        int row = m0 + wy * 64 + mf * 16 + ((lane >> 4) << 2);
#pragma unroll
        for (int nf = 0; nf < 2; ++nf) {
            int col = n0 + wx * 32 + nf * 16 + (lane & 15);
#pragma unroll
            for (int r = 0; r < 4; ++r)
                Cm[(size_t)(row + r) * Nn + col] = acc[mf][nf][r];
        }
    }
}

// ---- fused q+k fp64 NT GEMM: 64x64x16, f64 LDS, 8x4 register tile ----
// C f64 = X[4096,1024] @ W^T, W = Wq (n0g<256) else Wk.
// 128-thread blocks (2 waves), grid (8,64) = 512 blocks = 2 blocks/CU.
// Thread (ty=tid>>4 in 0..7, tx=tid&15): rows {16s+2ty+b} x cols
// {2tx+b, 32+2tx+b}. Per kk: 4 A-b128 (4 distinct bcast addrs, free) +
// 2 B-b128 (2-way, free) = 96 B for 32 FMA (3 B/FMA vs R12's 4) -> LDS
// 1536 cyc/tile/CU < FMA 2048 cyc/SIMD: FMA-bound. Staging writes 4-way
// (~10% overhead, accepted). Same per-element K-order => bit-identical.
__global__ __launch_bounds__(128) void gemm_qk_f64(const float* __restrict__ X,
                                                   const float* __restrict__ Wq,
                                                   const float* __restrict__ Wk,
                                                   double* __restrict__ q64,
                                                   double* __restrict__ k64) {
    __shared__ __align__(16) double As[16][66];
    __shared__ __align__(16) double Bs[16][66];
    const int tid = threadIdx.x;
    const int m0 = blockIdx.y * 64;
    const int n0g = blockIdx.x * 64;
    const bool isq = n0g < 256;
    const float* Wm = isq ? Wq : Wk;
    double* Cm = isq ? q64 : k64;
    const int n0 = isq ? n0g : n0g - 256;

    const int lr = tid >> 1;          // 0..63 staging row
    const int lc = (tid & 1) << 3;    // staging kk offset 0 or 8
    const int ty = tid >> 4;          // 0..7
    const int tx = tid & 15;          // 0..15

    double acc[8][4] = {};
    const float* Ap = X + (size_t)(m0 + lr) * 1024 + lc;
    const float* Bp = Wm + (size_t)(n0 + lr) * 1024 + lc;

    float4 a_pre0 = *(const float4*)(Ap);
    float4 a_pre1 = *(const float4*)(Ap + 4);
    float4 b_pre0 = *(const float4*)(Bp);
    float4 b_pre1 = *(const float4*)(Bp + 4);

    for (int t = 0; t < 64; ++t) {
        __syncthreads();
        As[lc + 0][lr] = (double)a_pre0.x; As[lc + 1][lr] = (double)a_pre0.y;
        As[lc + 2][lr] = (double)a_pre0.z; As[lc + 3][lr] = (double)a_pre0.w;
        As[lc + 4][lr] = (double)a_pre1.x; As[lc + 5][lr] = (double)a_pre1.y;
        As[lc + 6][lr] = (double)a_pre1.z; As[lc + 7][lr] = (double)a_pre1.w;
        Bs[lc + 0][lr] = (double)b_pre0.x; Bs[lc + 1][lr] = (double)b_pre0.y;
        Bs[lc + 2][lr] = (double)b_pre0.z; Bs[lc + 3][lr] = (double)b_pre0.w;
        Bs[lc + 4][lr] = (double)b_pre1.x; Bs[lc + 5][lr] = (double)b_pre1.y;
        Bs[lc + 6][lr] = (double)b_pre1.z; Bs[lc + 7][lr] = (double)b_pre1.w;
        __syncthreads();
        if (t < 63) {
            const float* An = Ap + (t + 1) * 16;
            const float* Bn = Bp + (t + 1) * 16;
            a_pre0 = *(const float4*)(An);
            a_pre1 = *(const float4*)(An + 4);
            b_pre0 = *(const float4*)(Bn);
            b_pre1 = *(const float4*)(Bn + 4);
        }
#pragma unroll
        for (int kk = 0; kk < 16; ++kk) {
            double2 a0v = *(const double2*)&As[kk][(ty << 1)];
            double2 a1v = *(const double2*)&As[kk][(ty << 1) + 16];
            double2 a2v = *(const double2*)&As[kk][(ty << 1) + 32];
            double2 a3v = *(const double2*)&As[kk][(ty << 1) + 48];
            double2 b0v = *(const double2*)&Bs[kk][(tx << 1)];
            double2 b1v = *(const double2*)&Bs[kk][(tx << 1) + 32];
            double a[8] = {a0v.x, a0v.y, a1v.x, a1v.y,
                           a2v.x, a2v.y, a3v.x, a3v.y};
            double b[4] = {b0v.x, b0v.y, b1v.x, b1v.y};
#pragma unroll
            for (int i = 0; i < 8; ++i)
#pragma unroll
                for (int j = 0; j < 4; ++j)
                    acc[i][j] += a[i] * b[j];
        }
    }
#pragma unroll
    for (int i = 0; i < 8; ++i) {
        int row = m0 + ((i >> 1) << 4) + (ty << 1) + (i & 1);
        size_t o = (size_t)row * 256 + n0 + (tx << 1);
        double2 r0 = {acc[i][0], acc[i][1]};
        double2 r1 = {acc[i][2], acc[i][3]};
        *(double2*)&Cm[o] = r0;
        *(double2*)&Cm[o + 32] = r1;
    }
}

// ------------- pass A: per-chunk KV fp32 (16x64) and Ksum fp64 (16) -------------
__global__ __launch_bounds__(256) void chunk_kv(const double* __restrict__ kg,
                                                const float* __restrict__ vg,
                                                float* __restrict__ KV,
                                                double* __restrict__ Ksum) {
    __shared__ double ksd[CHUNK][16];
    __shared__ float vs[CHUNK][64];
    const int c = blockIdx.x, bh = blockIdx.y;
    const int b = bh >> 4, h = bh & 15;
    const int n0 = b * L_ + c * CHUNK;
    const int tid = threadIdx.x;

    {
        int r = tid >> 1, o = (tid & 1) * 8;
        const double* kp = &kg[(size_t)(n0 + r) * 256 + h * 16 + o];
#pragma unroll
        for (int j = 0; j < 4; ++j)
            *(double2*)&ksd[r][o + j * 2] = *(const double2*)(kp + j * 2);
    }
    {
        int r = tid >> 1, half = (tid & 1) * 32;
        const float* vp = &vg[(size_t)(n0 + r) * 1024 + h * 64 + half];
#pragma unroll
        for (int j = 0; j < 8; ++j)
            *(float4*)&vs[r][half + j * 4] = *(const float4*)(vp + j * 4);
    }
    __syncthreads();

    const int f = tid >> 4;
    const int e4 = tid & 15;
    float a0 = 0.f, a1 = 0.f, a2 = 0.f, a3 = 0.f;
    double ksacc = 0.0;
    for (int l = 0; l < CHUNK; ++l) {
        double kd = ksd[l][f];
        float kv = (float)kd;
        float4 vv = *(const float4*)&vs[l][e4 << 2];
        a0 += kv * vv.x; a1 += kv * vv.y; a2 += kv * vv.z; a3 += kv * vv.w;
        ksacc += kd;
    }
    size_t o = ((size_t)bh * NCH + c) * 1024 + f * 64 + (e4 << 2);
    float4 r = {a0, a1, a2, a3};
    *(float4*)&KV[o] = r;
    if (e4 == 0) Ksum[((size_t)bh * NCH + c) * 16 + f] = ksacc;
}

// ------------- pass B: exclusive prefix over chunks -------------
__global__ __launch_bounds__(256) void prefix_kv(const float* __restrict__ KV,
                                                 const double* __restrict__ Ksum,
                                                 float* __restrict__ KVpre,
                                                 double* __restrict__ Kpre) {
    const int bh = blockIdx.x;
    const int t = threadIdx.x;
    float r0 = 0.f, r1 = 0.f, r2 = 0.f, r3 = 0.f;
    size_t base = (size_t)bh * NCH * 1024 + t * 4;
    for (int c = 0; c < NCH; ++c) {
        float4 w = {r0, r1, r2, r3};
        *(float4*)&KVpre[base + (size_t)c * 1024] = w;
        float4 cur = *(const float4*)&KV[base + (size_t)c * 1024];
        r0 += cur.x; r1 += cur.y; r2 += cur.z; r3 += cur.w;
    }
    if (t < 16) {
        double s = 0.0;
        size_t kb = (size_t)bh * NCH * 16 + t;
        for (int c = 0; c < NCH; ++c) {
            Kpre[kb + (size_t)c * 16] = s;
            s += Ksum[kb + (size_t)c * 16];
        }
    }
}

// ------------- pass C: per-chunk causal attention; writes y pre-split bf16x3 -------------
// Y3 written A-style [hi | lo | hi] (lo at +1024, hi copy at +2048).
__global__ __launch_bounds__(256) void attn_out(const double* __restrict__ qg,
                                                const double* __restrict__ kg,
                                                const float* __restrict__ vg,
                                                const float* __restrict__ kvpre,
                                                const double* __restrict__ kpreg,
                                                ushort* __restrict__ y3) {
    __shared__ double qs[CHUNK][16];
    __shared__ double ks[CHUNK][16];
    __shared__ float vs[CHUNK][64];
    __shared__ float s0[16][64];
    __shared__ double kp[16];
    const int c = blockIdx.x, bh = blockIdx.y;
    const int b = bh >> 4, h = bh & 15;
    const int n0 = b * L_ + c * CHUNK;
    const int tid = threadIdx.x;

    {
        int r = tid >> 1, o = (tid & 1) * 8;
        const double* qp = &qg[(size_t)(n0 + r) * 256 + h * 16 + o];
        const double* kptr = &kg[(size_t)(n0 + r) * 256 + h * 16 + o];
#pragma unroll
        for (int j = 0; j < 4; ++j) {
            *(double2*)&qs[r][o + j * 2] = *(const double2*)(qp + j * 2);
            *(double2*)&ks[r][o + j * 2] = *(const double2*)(kptr + j * 2);
        }
    }
    {
        int r = tid >> 1, half = (tid & 1) * 32;
        const float* vp = &vg[(size_t)(n0 + r) * 1024 + h * 64 + half];
#pragma unroll
        for (int j = 0; j < 8; ++j)
            *(float4*)&vs[r][half + j * 4] = *(const float4*)(vp + j * 4);
    }
    {
        float4 w = *(const float4*)&kvpre[((size_t)bh * NCH + c) * 1024 + tid * 4];
        *(float4*)&s0[0][tid * 4] = w;
        if (tid < 16) kp[tid] = kpreg[((size_t)bh * NCH + c) * 16 + tid];
    }
    __syncthreads();

    const int i = tid >> 1;
    const int half = (tid & 1) * 32;

    double qr[16];
#pragma unroll
    for (int f = 0; f < 16; ++f) qr[f] = qs[i][f];

    double denom = 0.0;
#pragma unroll
    for (int f = 0; f < 16; ++f) denom += qr[f] * kp[f];

    float acc[32] = {};
#pragma unroll
    for (int f = 0; f < 16; ++f) {
        float qf = (float)qr[f];
#pragma unroll
        for (int e = 0; e < 32; e += 4) {
            float4 sv = *(const float4*)&s0[f][half + e];
            acc[e + 0] += qf * sv.x; acc[e + 1] += qf * sv.y;
            acc[e + 2] += qf * sv.z; acc[e + 3] += qf * sv.w;
        }
    }
    for (int j = 0; j <= i; ++j) {
        double s64 = 0.0;
#pragma unroll
        for (int f = 0; f < 16; ++f) s64 += qr[f] * ks[j][f];
        denom += s64;
        float s = (float)s64;
        const float4* vj = (const float4*)&vs[j][half];
#pragma unroll
        for (int e4 = 0; e4 < 8; ++e4) {
            float4 vv = vj[e4];
            acc[e4 * 4 + 0] += s * vv.x; acc[e4 * 4 + 1] += s * vv.y;
            acc[e4 * 4 + 2] += s * vv.z; acc[e4 * 4 + 3] += s * vv.w;
        }
    }

    const float z = (float)(1.0 / (denom + 1e-12));
    ushort* yp = &y3[(size_t)(n0 + i) * K3 + h * 64 + half];
#pragma unroll
    for (int e4 = 0; e4 < 8; ++e4) {
        ushort hs[4], ls[4];
#pragma unroll
        for (int j = 0; j < 4; ++j) {
            float val = acc[e4 * 4 + j] * z;
            ushort hh = bf_rne(val);
            hs[j] = hh;
            ls[j] = bf_rne(val - bf_to_f(hh));
        }
        ushort4 hv = make_ushort4(hs[0], hs[1], hs[2], hs[3]);
        *(ushort4*)(yp + e4 * 4)        = hv;   // hi
        *(ushort4*)(yp + 1024 + e4 * 4) = make_ushort4(ls[0], ls[1], ls[2], ls[3]); // lo
        *(ushort4*)(yp + 2048 + e4 * 4) = hv;   // hi copy
    }
}

extern "C" void kernel_launch(void* const* d_in, const int* in_sizes, int n_in,
                              void* d_out, int out_size, void* d_ws, size_t ws_size,
                              hipStream_t stream) {
    const float* X  = (const float*)d_in[0];
    const float* Wq = (const float*)d_in[1];
    const float* Wk = (const float*)d_in[2];
    const float* Wv = (const float*)d_in[3];
    const float* Wo = (const float*)d_in[4];
    float* out = (float*)d_out;

    double* q64   = (double*)d_ws;                 // 8 MB
    double* k64   = q64 + 1048576;                 // 8 MB
    float*  v     = (float*)(k64 + 1048576);       // 16 MB
    float*  KV    = v + 4194304;                   // 2 MB
    float*  KVpre = KV + 524288;                   // 2 MB
    double* Ksum  = (double*)(KVpre + 524288);     // 64 KB
    double* Kpre  = Ksum + 8192;                   // 64 KB
    ushort* X3    = (ushort*)(Kpre + 8192);        // 24 MB (reused as Y3)
    ushort* Wv3   = X3 + (size_t)4096 * K3;        // 6 MB
    ushort* Wo3   = Wv3 + (size_t)1024 * K3;       // 6 MB
    // total ~72.2 MB

    dim3 blk(256);
    split3<<<2048, blk, 0, stream>>>(X, X3, 4096, 1024, 2048);   // A-style [hi|lo|hi]
    split3<<<512, blk, 0, stream>>>(Wv, Wv3, 1024, 2048, 1024);  // B-style [hi|hi|lo]
    split3<<<512, blk, 0, stream>>>(Wo, Wo3, 1024, 2048, 1024);  // B-style [hi|hi|lo]
    gemm_qk_f64<<<dim3(8, 64), dim3(128), 0, stream>>>(X, Wq, Wk, q64, k64);
    gemm_bf16x3<<<dim3(16, 32), blk, 0, stream>>>(X3, Wv3, v, 1024);
    chunk_kv<<<dim3(NCH, NBH), blk, 0, stream>>>(k64, v, KV, Ksum);
    prefix_kv<<<dim3(NBH), blk, 0, stream>>>(KV, Ksum, KVpre, Kpre);
    attn_out<<<dim3(NCH, NBH), blk, 0, stream>>>(q64, k64, v, KVpre, Kpre, X3);
    gemm_bf16x3<<<dim3(16, 32), blk, 0, stream>>>(X3, Wo3, out, 1024);
}

// Round 16
// 296.821 us; speedup vs baseline: 1.1910x; 1.1910x over previous
//
#include <hip/hip_runtime.h>

// LinearAttention: B=2, L=2048, D=1024, H=16, FD=16, HD=64. fp32 in/out.
// Denominator chain (q,k proj + cumsum + dots) stays fp64 (cancellation,
// z amplifies ~3e4). v-proj/out-proj: bf16x3 MFMA GEMMs; A-side stores
// [hi|lo] only (K-stride 2048) — the GEMM wraps A-addresses for t>=32 back
// to the hi segment (bit-identical products: AhiBhi, AloBhi, AhiBlo).
// B-side keeps [hi|hi|lo] (K-stride 3072).
// q,k proj: R12-proven fused vector-fp64 GEMM (TM=TN=64, TK=16, f64-staged
// LDS, conflict-free strided fragments, NO prefetch — R14 measured prefetch
// as -4us). qk is closed: LDS-port+barrier-bound at ~2.3x the fp64 floor
// (R12-R15 forensics). Lessons: no divergent-body fusion (R8); no split-K
// atomics (R9); bank-audit on mapping changes (R11); per-tile compute
// density rules (R13); never drop below 2 waves/SIMD (R15).

#define L_    2048
#define NROW  4096   // B*L
#define CHUNK 128
#define NCH   16
#define NBH   32
#define K3    3072   // B-operand K-stride (3 segments)
#define K2    2048   // A-operand K-stride (2 segments, hi wrap)

#define TM 64
#define TN 64

typedef __attribute__((ext_vector_type(8))) short short8v;
typedef __attribute__((ext_vector_type(4))) float floatx4;

__device__ __forceinline__ ushort bf_rne(float x) {
    unsigned u = __float_as_uint(x);
    return (ushort)((u + 0x7fffu + ((u >> 16) & 1u)) >> 16);
}
__device__ __forceinline__ float bf_to_f(ushort h) {
    return __uint_as_float(((unsigned)h) << 16);
}
__device__ __forceinline__ void gload16(const ushort* g, ushort* l) {
    __builtin_amdgcn_global_load_lds(
        (const __attribute__((address_space(1))) unsigned int*)g,
        (__attribute__((address_space(3))) unsigned int*)l, 16, 0, 0);
}

// ---- split fp32 [rows][1024] -> bf16 [rows][kstride]: hi at 0, lo at
// ---- lo_off, optional second hi copy at hi2_off (skipped if 0).
// A-style: kstride=2048, lo_off=1024, hi2_off=0 (dedup'd).
// B-style: kstride=3072, lo_off=2048, hi2_off=1024.
__global__ __launch_bounds__(256) void split3(const float* __restrict__ in,
                                              ushort* __restrict__ out3, int nrow,
                                              int kstride, int lo_off, int hi2_off) {
    int idx = blockIdx.x * 256 + threadIdx.x;
    int row = idx >> 7, g = idx & 127;
    if (row >= nrow) return;
    const float* p = in + (size_t)row * 1024 + g * 8;
    float4 x0 = *(const float4*)p, x1 = *(const float4*)(p + 4);
    float xs[8] = {x0.x, x0.y, x0.z, x0.w, x1.x, x1.y, x1.z, x1.w};
    ushort hs[8], ls[8];
#pragma unroll
    for (int j = 0; j < 8; ++j) {
        ushort h = bf_rne(xs[j]);
        hs[j] = h;
        ls[j] = bf_rne(xs[j] - bf_to_f(h));
    }
    ushort* o = out3 + (size_t)row * kstride + g * 8;
    ushort4 h0 = make_ushort4(hs[0], hs[1], hs[2], hs[3]);
    ushort4 h1 = make_ushort4(hs[4], hs[5], hs[6], hs[7]);
    *(ushort4*)(o)              = h0;
    *(ushort4*)(o + 4)          = h1;
    *(ushort4*)(o + lo_off)     = make_ushort4(ls[0], ls[1], ls[2], ls[3]);
    *(ushort4*)(o + lo_off + 4) = make_ushort4(ls[4], ls[5], ls[6], ls[7]);
    if (hi2_off) {
        *(ushort4*)(o + hi2_off)     = h0;
        *(ushort4*)(o + hi2_off + 4) = h1;
    }
}

// -------- bf16 NT GEMM: C[M,1024] f32 = A2[M,2048(wrap)] @ B3[1024,3072]^T --------
// Tile 128(M)x64(N), BK=64, 4 waves 2x2 (wave = 64x32), dbuf LDS 48KB ->
// 3 blocks/CU, gload_lds w=16, grid (16,32) = 512 blocks. (R10-proven)
// A-addresses wrap: K-step t>=32 reads A at (t-32) (hi segment re-read).
__global__ __launch_bounds__(256) void gemm_bf16x3(const ushort* __restrict__ A2,
                                                   const ushort* __restrict__ B3,
                                                   float* __restrict__ Cm, int Nn) {
    __shared__ ushort As[2][8192];
    __shared__ ushort Bs[2][4096];
    const int tid = threadIdx.x;
    const int lane = tid & 63;
    const int wy = tid >> 7;
    const int wx = (tid >> 6) & 1;
    const int m0 = blockIdx.y * 128;
    const int n0 = blockIdx.x * 64;

    const int arow = tid >> 3;                   // 0..31
    const int aslot = (tid & 7) ^ (arow & 7);    // inverse-swizzled source slot
    const ushort* pA[4];
    const ushort* pB[2];
#pragma unroll
    for (int i = 0; i < 4; ++i)
        pA[i] = A2 + (size_t)(m0 + i * 32 + arow) * K2 + aslot * 8;
#pragma unroll
    for (int i = 0; i < 2; ++i)
        pB[i] = B3 + (size_t)(n0 + i * 32 + arow) * K3 + aslot * 8;

#define STAGE(buf, tt)                                                     \
    do {                                                                   \
        const int kkA = ((tt) < 32 ? (tt) : (tt) - 32) * 64;               \
        const int kkB = (tt) * 64;                                         \
        _Pragma("unroll") for (int i = 0; i < 4; ++i)                      \
            gload16(pA[i] + kkA, &As[buf][i * 2048 + tid * 8]);            \
        _Pragma("unroll") for (int i = 0; i < 2; ++i)                      \
            gload16(pB[i] + kkB, &Bs[buf][i * 2048 + tid * 8]);            \
    } while (0)

    const int abase = (wy * 64 + (lane & 15)) * 64;
    const int bbase = (wx * 32 + (lane & 15)) * 64;

    floatx4 acc[4][2] = {};
    STAGE(0, 0);
    for (int t = 0; t < 48; ++t) {
        const int cur = t & 1;
        __syncthreads();
        if (t < 47) STAGE(1 - cur, t + 1);
#pragma unroll
        for (int ksub = 0; ksub < 2; ++ksub) {
            const int so = ((((lane >> 4) | (ksub << 2)) ^ (lane & 7)) << 3);
            short8v a[4], b[2];
#pragma unroll
            for (int mf = 0; mf < 4; ++mf)
                a[mf] = *(const short8v*)&As[cur][abase + mf * 1024 + so];
#pragma unroll
            for (int nf = 0; nf < 2; ++nf)
                b[nf] = *(const short8v*)&Bs[cur][bbase + nf * 1024 + so];
#pragma unroll
            for (int mf = 0; mf < 4; ++mf)
#pragma unroll
                for (int nf = 0; nf < 2; ++nf)
                    acc[mf][nf] = __builtin_amdgcn_mfma_f32_16x16x32_bf16(
                        a[mf], b[nf], acc[mf][nf], 0, 0, 0);
        }
    }
#undef STAGE

#pragma unroll
    for (int mf = 0; mf < 4; ++mf) {
        int row = m0 + wy * 64 + mf * 16 + ((lane >> 4) << 2);
#pragma unroll
        for (int nf = 0; nf < 2; ++nf) {
            int col = n0 + wx * 32 + nf * 16 + (lane & 15);
#pragma unroll
            for (int r = 0; r < 4; ++r)
                Cm[(size_t)(row + r) * Nn + col] = acc[mf][nf][r];
        }
    }
}

// ---- fused q+k fp64 NT GEMM, TK=16, f64-staged LDS, strided fragments ----
// (R12-proven exact: no prefetch — R14 measured prefetch as a 4us loss.)
// C f64 = X[4096,1024] @ W^T, W = Wq (n0g<256) else Wk. Tile 64x64.
// Thread (ty,tx) owns rows {2ty,2ty+1,32+2ty,33+2ty} x cols {2tx,2tx+1,
// 32+2tx,33+2tx}. All ds_read_b128 <=2-way (free). Grid (8,64) = 512.
__global__ __launch_bounds__(256) void gemm_qk_f64(const float* __restrict__ X,
                                                   const float* __restrict__ Wq,
                                                   const float* __restrict__ Wk,
                                                   double* __restrict__ q64,
                                                   double* __restrict__ k64) {
    __shared__ __align__(16) double As[16][66];
    __shared__ __align__(16) double Bs[16][66];
    const int tid = threadIdx.x;
    const int m0 = blockIdx.y * TM;
    const int n0g = blockIdx.x * TN;
    const bool isq = n0g < 256;
    const float* Wm = isq ? Wq : Wk;
    double* Cm = isq ? q64 : k64;
    const int n0 = isq ? n0g : n0g - 256;

    const int lr = tid >> 2;          // 0..63 staging row
    const int lc = (tid & 3) << 2;    // staging kk offset 0,4,8,12
    const int ty = tid >> 4;          // 0..15
    const int tx = tid & 15;          // 0..15

    double acc[4][4] = {};
    const float* Ap = X + (size_t)(m0 + lr) * 1024 + lc;
    const float* Bp = Wm + (size_t)(n0 + lr) * 1024 + lc;

    for (int k0 = 0; k0 < 1024; k0 += 16) {
        float4 a0 = *(const float4*)(Ap + k0);
        float4 b0 = *(const float4*)(Bp + k0);
        __syncthreads();
        As[lc + 0][lr] = (double)a0.x; As[lc + 1][lr] = (double)a0.y;
        As[lc + 2][lr] = (double)a0.z; As[lc + 3][lr] = (double)a0.w;
        Bs[lc + 0][lr] = (double)b0.x; Bs[lc + 1][lr] = (double)b0.y;
        Bs[lc + 2][lr] = (double)b0.z; Bs[lc + 3][lr] = (double)b0.w;
        __syncthreads();
#pragma unroll
        for (int kk = 0; kk < 16; ++kk) {
            double2 a0v = *(const double2*)&As[kk][ty << 1];
            double2 a1v = *(const double2*)&As[kk][(ty << 1) + 32];
            double2 b0v = *(const double2*)&Bs[kk][tx << 1];
            double2 b1v = *(const double2*)&Bs[kk][(tx << 1) + 32];
            double a[4] = {a0v.x, a0v.y, a1v.x, a1v.y};
            double b[4] = {b0v.x, b0v.y, b1v.x, b1v.y};
#pragma unroll
            for (int i = 0; i < 4; ++i)
#pragma unroll
                for (int j = 0; j < 4; ++j)
                    acc[i][j] += a[i] * b[j];
        }
    }
#pragma unroll
    for (int i = 0; i < 4; ++i) {
        int row = m0 + ((i >> 1) << 5) + (ty << 1) + (i & 1);
        size_t o = (size_t)row * 256 + n0 + (tx << 1);
        double2 r0 = {acc[i][0], acc[i][1]};
        double2 r1 = {acc[i][2], acc[i][3]};
        *(double2*)&Cm[o] = r0;
        *(double2*)&Cm[o + 32] = r1;
    }
}

// ------------- pass A: per-chunk KV fp32 (16x64) and Ksum fp64 (16) -------------
__global__ __launch_bounds__(256) void chunk_kv(const double* __restrict__ kg,
                                                const float* __restrict__ vg,
                                                float* __restrict__ KV,
                                                double* __restrict__ Ksum) {
    __shared__ double ksd[CHUNK][16];
    __shared__ float vs[CHUNK][64];
    const int c = blockIdx.x, bh = blockIdx.y;
    const int b = bh >> 4, h = bh & 15;
    const int n0 = b * L_ + c * CHUNK;
    const int tid = threadIdx.x;

    {
        int r = tid >> 1, o = (tid & 1) * 8;
        const double* kp = &kg[(size_t)(n0 + r) * 256 + h * 16 + o];
#pragma unroll
        for (int j = 0; j < 4; ++j)
            *(double2*)&ksd[r][o + j * 2] = *(const double2*)(kp + j * 2);
    }
    {
        int r = tid >> 1, half = (tid & 1) * 32;
        const float* vp = &vg[(size_t)(n0 + r) * 1024 + h * 64 + half];
#pragma unroll
        for (int j = 0; j < 8; ++j)
            *(float4*)&vs[r][half + j * 4] = *(const float4*)(vp + j * 4);
    }
    __syncthreads();

    const int f = tid >> 4;
    const int e4 = tid & 15;
    float a0 = 0.f, a1 = 0.f, a2 = 0.f, a3 = 0.f;
    double ksacc = 0.0;
    for (int l = 0; l < CHUNK; ++l) {
        double kd = ksd[l][f];
        float kv = (float)kd;
        float4 vv = *(const float4*)&vs[l][e4 << 2];
        a0 += kv * vv.x; a1 += kv * vv.y; a2 += kv * vv.z; a3 += kv * vv.w;
        ksacc += kd;
    }
    size_t o = ((size_t)bh * NCH + c) * 1024 + f * 64 + (e4 << 2);
    float4 r = {a0, a1, a2, a3};
    *(float4*)&KV[o] = r;
    if (e4 == 0) Ksum[((size_t)bh * NCH + c) * 16 + f] = ksacc;
}

// ------------- pass B: exclusive prefix over chunks -------------
__global__ __launch_bounds__(256) void prefix_kv(const float* __restrict__ KV,
                                                 const double* __restrict__ Ksum,
                                                 float* __restrict__ KVpre,
                                                 double* __restrict__ Kpre) {
    const int bh = blockIdx.x;
    const int t = threadIdx.x;
    float r0 = 0.f, r1 = 0.f, r2 = 0.f, r3 = 0.f;
    size_t base = (size_t)bh * NCH * 1024 + t * 4;
    for (int c = 0; c < NCH; ++c) {
        float4 w = {r0, r1, r2, r3};
        *(float4*)&KVpre[base + (size_t)c * 1024] = w;
        float4 cur = *(const float4*)&KV[base + (size_t)c * 1024];
        r0 += cur.x; r1 += cur.y; r2 += cur.z; r3 += cur.w;
    }
    if (t < 16) {
        double s = 0.0;
        size_t kb = (size_t)bh * NCH * 16 + t;
        for (int c = 0; c < NCH; ++c) {
            Kpre[kb + (size_t)c * 16] = s;
            s += Ksum[kb + (size_t)c * 16];
        }
    }
}

// ------------- pass C: per-chunk causal attention; writes y split bf16x2 -------------
// Y2 written A-style [hi | lo] (lo at +1024, K-stride 2048; hi re-read by
// the GEMM's A-wrap for t>=32).
__global__ __launch_bounds__(256) void attn_out(const double* __restrict__ qg,
                                                const double* __restrict__ kg,
                                                const float* __restrict__ vg,
                                                const float* __restrict__ kvpre,
                                                const double* __restrict__ kpreg,
                                                ushort* __restrict__ y2) {
    __shared__ double qs[CHUNK][16];
    __shared__ double ks[CHUNK][16];
    __shared__ float vs[CHUNK][64];
    __shared__ float s0[16][64];
    __shared__ double kp[16];
    const int c = blockIdx.x, bh = blockIdx.y;
    const int b = bh >> 4, h = bh & 15;
    const int n0 = b * L_ + c * CHUNK;
    const int tid = threadIdx.x;

    {
        int r = tid >> 1, o = (tid & 1) * 8;
        const double* qp = &qg[(size_t)(n0 + r) * 256 + h * 16 + o];
        const double* kptr = &kg[(size_t)(n0 + r) * 256 + h * 16 + o];
#pragma unroll
        for (int j = 0; j < 4; ++j) {
            *(double2*)&qs[r][o + j * 2] = *(const double2*)(qp + j * 2);
            *(double2*)&ks[r][o + j * 2] = *(const double2*)(kptr + j * 2);
        }
    }
    {
        int r = tid >> 1, half = (tid & 1) * 32;
        const float* vp = &vg[(size_t)(n0 + r) * 1024 + h * 64 + half];
#pragma unroll
        for (int j = 0; j < 8; ++j)
            *(float4*)&vs[r][half + j * 4] = *(const float4*)(vp + j * 4);
    }
    {
        float4 w = *(const float4*)&kvpre[((size_t)bh * NCH + c) * 1024 + tid * 4];
        *(float4*)&s0[0][tid * 4] = w;
        if (tid < 16) kp[tid] = kpreg[((size_t)bh * NCH + c) * 16 + tid];
    }
    __syncthreads();

    const int i = tid >> 1;
    const int half = (tid & 1) * 32;

    double qr[16];
#pragma unroll
    for (int f = 0; f < 16; ++f) qr[f] = qs[i][f];

    double denom = 0.0;
#pragma unroll
    for (int f = 0; f < 16; ++f) denom += qr[f] * kp[f];

    float acc[32] = {};
#pragma unroll
    for (int f = 0; f < 16; ++f) {
        float qf = (float)qr[f];
#pragma unroll
        for (int e = 0; e < 32; e += 4) {
            float4 sv = *(const float4*)&s0[f][half + e];
            acc[e + 0] += qf * sv.x; acc[e + 1] += qf * sv.y;
            acc[e + 2] += qf * sv.z; acc[e + 3] += qf * sv.w;
        }
    }
    for (int j = 0; j <= i; ++j) {
        double s64 = 0.0;
#pragma unroll
        for (int f = 0; f < 16; ++f) s64 += qr[f] * ks[j][f];
        denom += s64;
        float s = (float)s64;
        const float4* vj = (const float4*)&vs[j][half];
#pragma unroll
        for (int e4 = 0; e4 < 8; ++e4) {
            float4 vv = vj[e4];
            acc[e4 * 4 + 0] += s * vv.x; acc[e4 * 4 + 1] += s * vv.y;
            acc[e4 * 4 + 2] += s * vv.z; acc[e4 * 4 + 3] += s * vv.w;
        }
    }

    const float z = (float)(1.0 / (denom + 1e-12));
    ushort* yp = &y2[(size_t)(n0 + i) * K2 + h * 64 + half];
#pragma unroll
    for (int e4 = 0; e4 < 8; ++e4) {
        ushort hs[4], ls[4];
#pragma unroll
        for (int j = 0; j < 4; ++j) {
            float val = acc[e4 * 4 + j] * z;
            ushort hh = bf_rne(val);
            hs[j] = hh;
            ls[j] = bf_rne(val - bf_to_f(hh));
        }
        *(ushort4*)(yp + e4 * 4)        = make_ushort4(hs[0], hs[1], hs[2], hs[3]);
        *(ushort4*)(yp + 1024 + e4 * 4) = make_ushort4(ls[0], ls[1], ls[2], ls[3]);
    }
}

extern "C" void kernel_launch(void* const* d_in, const int* in_sizes, int n_in,
                              void* d_out, int out_size, void* d_ws, size_t ws_size,
                              hipStream_t stream) {
    const float* X  = (const float*)d_in[0];
    const float* Wq = (const float*)d_in[1];
    const float* Wk = (const float*)d_in[2];
    const float* Wv = (const float*)d_in[3];
    const float* Wo = (const float*)d_in[4];
    float* out = (float*)d_out;

    double* q64   = (double*)d_ws;                 // 8 MB
    double* k64   = q64 + 1048576;                 // 8 MB
    float*  v     = (float*)(k64 + 1048576);       // 16 MB
    float*  KV    = v + 4194304;                   // 2 MB
    float*  KVpre = KV + 524288;                   // 2 MB
    double* Ksum  = (double*)(KVpre + 524288);     // 64 KB
    double* Kpre  = Ksum + 8192;                   // 64 KB
    ushort* X2    = (ushort*)(Kpre + 8192);        // 4096*2048 u16 = 16 MB (reused as Y2)
    ushort* Wv3   = X2 + (size_t)4096 * K2;        // 1024*3072 u16 = 6 MB
    ushort* Wo3   = Wv3 + (size_t)1024 * K3;       // 6 MB
    // total ~64.2 MB

    dim3 blk(256);
    split3<<<2048, blk, 0, stream>>>(X, X2, 4096, K2, 1024, 0);      // A-style [hi|lo]
    split3<<<512, blk, 0, stream>>>(Wv, Wv3, 1024, K3, 2048, 1024);  // B-style [hi|hi|lo]
    split3<<<512, blk, 0, stream>>>(Wo, Wo3, 1024, K3, 2048, 1024);  // B-style [hi|hi|lo]
    gemm_qk_f64<<<dim3(8, 64), blk, 0, stream>>>(X, Wq, Wk, q64, k64);
    gemm_bf16x3<<<dim3(16, 32), blk, 0, stream>>>(X2, Wv3, v, 1024);
    chunk_kv<<<dim3(NCH, NBH), blk, 0, stream>>>(k64, v, KV, Ksum);
    prefix_kv<<<dim3(NBH), blk, 0, stream>>>(KV, Ksum, KVpre, Kpre);
    attn_out<<<dim3(NCH, NBH), blk, 0, stream>>>(q64, k64, v, KVpre, Kpre, X2);
    gemm_bf16x3<<<dim3(16, 32), blk, 0, stream>>>(X2, Wo3, out, 1024);
}

// Round 17
// 287.780 us; speedup vs baseline: 1.2284x; 1.0314x over previous
//
#include <hip/hip_runtime.h>

// LinearAttention: B=2, L=2048, D=1024, H=16, FD=16, HD=64. fp32 in/out.
// Denominator chain (q,k proj + cumsum + dots) stays fp64 (cancellation,
// z amplifies ~3e4). v-proj/out-proj: bf16x3 MFMA GEMMs (A3=[Ahi|Alo|Ahi],
// B3=[Bhi|Bhi|Blo]) + R17: XCD-aware chunked block swizzle (bijective,
// 512%8==0) — each XCD gets 4 contiguous m-panels (A 3MB fits its 4MB L2).
// q,k proj: R12-proven fused vector-fp64 GEMM (TM=TN=64, TK=16, f64-staged
// LDS, conflict-free strided fragments, no prefetch). qk is CLOSED:
// LDS-port+barrier-bound at 2.3x fp64 floor (R13/R14/R15 all falsified).
// Lessons: no divergent-body fusion (R8); no split-K atomics (R9);
// bank-audit on mapping changes (R11); per-tile compute density rules
// (R13); never drop below 2 waves/SIMD (R15); A-dedup wrap = flat (R16).

#define L_    2048
#define NROW  4096   // B*L
#define CHUNK 128
#define NCH   16
#define NBH   32
#define K3    3072

#define TM 64
#define TN 64

typedef __attribute__((ext_vector_type(8))) short short8v;
typedef __attribute__((ext_vector_type(4))) float floatx4;

__device__ __forceinline__ ushort bf_rne(float x) {
    unsigned u = __float_as_uint(x);
    return (ushort)((u + 0x7fffu + ((u >> 16) & 1u)) >> 16);
}
__device__ __forceinline__ float bf_to_f(ushort h) {
    return __uint_as_float(((unsigned)h) << 16);
}
__device__ __forceinline__ void gload16(const ushort* g, ushort* l) {
    __builtin_amdgcn_global_load_lds(
        (const __attribute__((address_space(1))) unsigned int*)g,
        (__attribute__((address_space(3))) unsigned int*)l, 16, 0, 0);
}

// ---- split fp32 [rows][1024] -> bf16 [rows][3072]: hi at 0 and hi2_off,
// ---- lo at lo_off.  A-style: lo_off=1024,hi2=2048. B-style: lo_off=2048,hi2=1024.
__global__ __launch_bounds__(256) void split3(const float* __restrict__ in,
                                              ushort* __restrict__ out3, int nrow,
                                              int lo_off, int hi2_off) {
    int idx = blockIdx.x * 256 + threadIdx.x;
    int row = idx >> 7, g = idx & 127;
    if (row >= nrow) return;
    const float* p = in + (size_t)row * 1024 + g * 8;
    float4 x0 = *(const float4*)p, x1 = *(const float4*)(p + 4);
    float xs[8] = {x0.x, x0.y, x0.z, x0.w, x1.x, x1.y, x1.z, x1.w};
    ushort hs[8], ls[8];
#pragma unroll
    for (int j = 0; j < 8; ++j) {
        ushort h = bf_rne(xs[j]);
        hs[j] = h;
        ls[j] = bf_rne(xs[j] - bf_to_f(h));
    }
    ushort* o = out3 + (size_t)row * 3072 + g * 8;
    ushort4 h0 = make_ushort4(hs[0], hs[1], hs[2], hs[3]);
    ushort4 h1 = make_ushort4(hs[4], hs[5], hs[6], hs[7]);
    *(ushort4*)(o)               = h0;
    *(ushort4*)(o + 4)           = h1;
    *(ushort4*)(o + hi2_off)     = h0;
    *(ushort4*)(o + hi2_off + 4) = h1;
    *(ushort4*)(o + lo_off)      = make_ushort4(ls[0], ls[1], ls[2], ls[3]);
    *(ushort4*)(o + lo_off + 4)  = make_ushort4(ls[4], ls[5], ls[6], ls[7]);
}

// -------- bf16 NT GEMM: C[M,1024] f32 = A3[M,3072] @ B3[1024,3072]^T --------
// Tile 128(M)x64(N), BK=64, 4 waves 2x2 (wave = 64x32), dbuf LDS 48KB ->
// 3 blocks/CU, gload_lds w=16, 1-D grid 512 with XCD-chunked swizzle:
// swz = (bid&7)*64 + bid>>3 (bijective) -> XCD c hosts m-panels 4c..4c+3
// for all 16 n-tiles: A working set 3MB/XCD (L2-resident, 16x reuse).
__global__ __launch_bounds__(256) void gemm_bf16x3(const ushort* __restrict__ A3,
                                                   const ushort* __restrict__ B3,
                                                   float* __restrict__ Cm, int Nn) {
    __shared__ ushort As[2][8192];
    __shared__ ushort Bs[2][4096];
    const int tid = threadIdx.x;
    const int lane = tid & 63;
    const int wy = tid >> 7;
    const int wx = (tid >> 6) & 1;
    const int bid = blockIdx.x;
    const int swz = (bid & 7) * (gridDim.x >> 3) + (bid >> 3);
    const int m0 = (swz >> 4) * 128;
    const int n0 = (swz & 15) * 64;

    const int arow = tid >> 3;                   // 0..31
    const int aslot = (tid & 7) ^ (arow & 7);    // inverse-swizzled source slot
    const ushort* pA[4];
    const ushort* pB[2];
#pragma unroll
    for (int i = 0; i < 4; ++i)
        pA[i] = A3 + (size_t)(m0 + i * 32 + arow) * K3 + aslot * 8;
#pragma unroll
    for (int i = 0; i < 2; ++i)
        pB[i] = B3 + (size_t)(n0 + i * 32 + arow) * K3 + aslot * 8;

#define STAGE(buf, kk)                                              \
    do {                                                            \
        _Pragma("unroll") for (int i = 0; i < 4; ++i)               \
            gload16(pA[i] + (kk), &As[buf][i * 2048 + tid * 8]);    \
        _Pragma("unroll") for (int i = 0; i < 2; ++i)               \
            gload16(pB[i] + (kk), &Bs[buf][i * 2048 + tid * 8]);    \
    } while (0)

    const int abase = (wy * 64 + (lane & 15)) * 64;
    const int bbase = (wx * 32 + (lane & 15)) * 64;

    floatx4 acc[4][2] = {};
    STAGE(0, 0);
    for (int t = 0; t < 48; ++t) {
        const int cur = t & 1;
        __syncthreads();
        if (t < 47) STAGE(1 - cur, (t + 1) * 64);
#pragma unroll
        for (int ksub = 0; ksub < 2; ++ksub) {
            const int so = ((((lane >> 4) | (ksub << 2)) ^ (lane & 7)) << 3);
            short8v a[4], b[2];
#pragma unroll
            for (int mf = 0; mf < 4; ++mf)
                a[mf] = *(const short8v*)&As[cur][abase + mf * 1024 + so];
#pragma unroll
            for (int nf = 0; nf < 2; ++nf)
                b[nf] = *(const short8v*)&Bs[cur][bbase + nf * 1024 + so];
#pragma unroll
            for (int mf = 0; mf < 4; ++mf)
#pragma unroll
                for (int nf = 0; nf < 2; ++nf)
                    acc[mf][nf] = __builtin_amdgcn_mfma_f32_16x16x32_bf16(
                        a[mf], b[nf], acc[mf][nf], 0, 0, 0);
        }
    }
#undef STAGE

#pragma unroll
    for (int mf = 0; mf < 4; ++mf) {
        int row = m0 + wy * 64 + mf * 16 + ((lane >> 4) << 2);
#pragma unroll
        for (int nf = 0; nf < 2; ++nf) {
            int col = n0 + wx * 32 + nf * 16 + (lane & 15);
#pragma unroll
            for (int r = 0; r < 4; ++r)
                Cm[(size_t)(row + r) * Nn + col] = acc[mf][nf][r];
        }
    }
}

// ---- fused q+k fp64 NT GEMM, TK=16, f64-staged LDS, strided fragments ----
// (R12-proven exact.) C f64 = X[4096,1024] @ W^T, W = Wq (n0g<256) else Wk.
// Tile 64x64. Thread (ty,tx) owns rows {2ty,2ty+1,32+2ty,33+2ty} x cols
// {2tx,2tx+1,32+2tx,33+2tx}. All ds_read_b128 <=2-way (free). Grid (8,64).
__global__ __launch_bounds__(256) void gemm_qk_f64(const float* __restrict__ X,
                                                   const float* __restrict__ Wq,
                                                   const float* __restrict__ Wk,
                                                   double* __restrict__ q64,
                                                   double* __restrict__ k64) {
    __shared__ __align__(16) double As[16][66];
    __shared__ __align__(16) double Bs[16][66];
    const int tid = threadIdx.x;
    const int m0 = blockIdx.y * TM;
    const int n0g = blockIdx.x * TN;
    const bool isq = n0g < 256;
    const float* Wm = isq ? Wq : Wk;
    double* Cm = isq ? q64 : k64;
    const int n0 = isq ? n0g : n0g - 256;

    const int lr = tid >> 2;          // 0..63 staging row
    const int lc = (tid & 3) << 2;    // staging kk offset 0,4,8,12
    const int ty = tid >> 4;          // 0..15
    const int tx = tid & 15;          // 0..15

    double acc[4][4] = {};
    const float* Ap = X + (size_t)(m0 + lr) * 1024 + lc;
    const float* Bp = Wm + (size_t)(n0 + lr) * 1024 + lc;

    for (int k0 = 0; k0 < 1024; k0 += 16) {
        float4 a0 = *(const float4*)(Ap + k0);
        float4 b0 = *(const float4*)(Bp + k0);
        __syncthreads();
        As[lc + 0][lr] = (double)a0.x; As[lc + 1][lr] = (double)a0.y;
        As[lc + 2][lr] = (double)a0.z; As[lc + 3][lr] = (double)a0.w;
        Bs[lc + 0][lr] = (double)b0.x; Bs[lc + 1][lr] = (double)b0.y;
        Bs[lc + 2][lr] = (double)b0.z; Bs[lc + 3][lr] = (double)b0.w;
        __syncthreads();
#pragma unroll
        for (int kk = 0; kk < 16; ++kk) {
            double2 a0v = *(const double2*)&As[kk][ty << 1];
            double2 a1v = *(const double2*)&As[kk][(ty << 1) + 32];
            double2 b0v = *(const double2*)&Bs[kk][tx << 1];
            double2 b1v = *(const double2*)&Bs[kk][(tx << 1) + 32];
            double a[4] = {a0v.x, a0v.y, a1v.x, a1v.y};
            double b[4] = {b0v.x, b0v.y, b1v.x, b1v.y};
#pragma unroll
            for (int i = 0; i < 4; ++i)
#pragma unroll
                for (int j = 0; j < 4; ++j)
                    acc[i][j] += a[i] * b[j];
        }
    }
#pragma unroll
    for (int i = 0; i < 4; ++i) {
        int row = m0 + ((i >> 1) << 5) + (ty << 1) + (i & 1);
        size_t o = (size_t)row * 256 + n0 + (tx << 1);
        double2 r0 = {acc[i][0], acc[i][1]};
        double2 r1 = {acc[i][2], acc[i][3]};
        *(double2*)&Cm[o] = r0;
        *(double2*)&Cm[o + 32] = r1;
    }
}

// ------------- pass A: per-chunk KV fp32 (16x64) and Ksum fp64 (16) -------------
__global__ __launch_bounds__(256) void chunk_kv(const double* __restrict__ kg,
                                                const float* __restrict__ vg,
                                                float* __restrict__ KV,
                                                double* __restrict__ Ksum) {
    __shared__ double ksd[CHUNK][16];
    __shared__ float vs[CHUNK][64];
    const int c = blockIdx.x, bh = blockIdx.y;
    const int b = bh >> 4, h = bh & 15;
    const int n0 = b * L_ + c * CHUNK;
    const int tid = threadIdx.x;

    {
        int r = tid >> 1, o = (tid & 1) * 8;
        const double* kp = &kg[(size_t)(n0 + r) * 256 + h * 16 + o];
#pragma unroll
        for (int j = 0; j < 4; ++j)
            *(double2*)&ksd[r][o + j * 2] = *(const double2*)(kp + j * 2);
    }
    {
        int r = tid >> 1, half = (tid & 1) * 32;
        const float* vp = &vg[(size_t)(n0 + r) * 1024 + h * 64 + half];
#pragma unroll
        for (int j = 0; j < 8; ++j)
            *(float4*)&vs[r][half + j * 4] = *(const float4*)(vp + j * 4);
    }
    __syncthreads();

    const int f = tid >> 4;
    const int e4 = tid & 15;
    float a0 = 0.f, a1 = 0.f, a2 = 0.f, a3 = 0.f;
    double ksacc = 0.0;
    for (int l = 0; l < CHUNK; ++l) {
        double kd = ksd[l][f];
        float kv = (float)kd;
        float4 vv = *(const float4*)&vs[l][e4 << 2];
        a0 += kv * vv.x; a1 += kv * vv.y; a2 += kv * vv.z; a3 += kv * vv.w;
        ksacc += kd;
    }
    size_t o = ((size_t)bh * NCH + c) * 1024 + f * 64 + (e4 << 2);
    float4 r = {a0, a1, a2, a3};
    *(float4*)&KV[o] = r;
    if (e4 == 0) Ksum[((size_t)bh * NCH + c) * 16 + f] = ksacc;
}

// ------------- pass B: exclusive prefix over chunks -------------
__global__ __launch_bounds__(256) void prefix_kv(const float* __restrict__ KV,
                                                 const double* __restrict__ Ksum,
                                                 float* __restrict__ KVpre,
                                                 double* __restrict__ Kpre) {
    const int bh = blockIdx.x;
    const int t = threadIdx.x;
    float r0 = 0.f, r1 = 0.f, r2 = 0.f, r3 = 0.f;
    size_t base = (size_t)bh * NCH * 1024 + t * 4;
    for (int c = 0; c < NCH; ++c) {
        float4 w = {r0, r1, r2, r3};
        *(float4*)&KVpre[base + (size_t)c * 1024] = w;
        float4 cur = *(const float4*)&KV[base + (size_t)c * 1024];
        r0 += cur.x; r1 += cur.y; r2 += cur.z; r3 += cur.w;
    }
    if (t < 16) {
        double s = 0.0;
        size_t kb = (size_t)bh * NCH * 16 + t;
        for (int c = 0; c < NCH; ++c) {
            Kpre[kb + (size_t)c * 16] = s;
            s += Ksum[kb + (size_t)c * 16];
        }
    }
}

// ------------- pass C: per-chunk causal attention; writes y pre-split bf16x3 -------------
// Y3 written A-style [hi | lo | hi] (lo at +1024, hi copy at +2048).
__global__ __launch_bounds__(256) void attn_out(const double* __restrict__ qg,
                                                const double* __restrict__ kg,
                                                const float* __restrict__ vg,
                                                const float* __restrict__ kvpre,
                                                const double* __restrict__ kpreg,
                                                ushort* __restrict__ y3) {
    __shared__ double qs[CHUNK][16];
    __shared__ double ks[CHUNK][16];
    __shared__ float vs[CHUNK][64];
    __shared__ float s0[16][64];
    __shared__ double kp[16];
    const int c = blockIdx.x, bh = blockIdx.y;
    const int b = bh >> 4, h = bh & 15;
    const int n0 = b * L_ + c * CHUNK;
    const int tid = threadIdx.x;

    {
        int r = tid >> 1, o = (tid & 1) * 8;
        const double* qp = &qg[(size_t)(n0 + r) * 256 + h * 16 + o];
        const double* kptr = &kg[(size_t)(n0 + r) * 256 + h * 16 + o];
#pragma unroll
        for (int j = 0; j < 4; ++j) {
            *(double2*)&qs[r][o + j * 2] = *(const double2*)(qp + j * 2);
            *(double2*)&ks[r][o + j * 2] = *(const double2*)(kptr + j * 2);
        }
    }
    {
        int r = tid >> 1, half = (tid & 1) * 32;
        const float* vp = &vg[(size_t)(n0 + r) * 1024 + h * 64 + half];
#pragma unroll
        for (int j = 0; j < 8; ++j)
            *(float4*)&vs[r][half + j * 4] = *(const float4*)(vp + j * 4);
    }
    {
        float4 w = *(const float4*)&kvpre[((size_t)bh * NCH + c) * 1024 + tid * 4];
        *(float4*)&s0[0][tid * 4] = w;
        if (tid < 16) kp[tid] = kpreg[((size_t)bh * NCH + c) * 16 + tid];
    }
    __syncthreads();

    const int i = tid >> 1;
    const int half = (tid & 1) * 32;

    double qr[16];
#pragma unroll
    for (int f = 0; f < 16; ++f) qr[f] = qs[i][f];

    double denom = 0.0;
#pragma unroll
    for (int f = 0; f < 16; ++f) denom += qr[f] * kp[f];

    float acc[32] = {};
#pragma unroll
    for (int f = 0; f < 16; ++f) {
        float qf = (float)qr[f];
#pragma unroll
        for (int e = 0; e < 32; e += 4) {
            float4 sv = *(const float4*)&s0[f][half + e];
            acc[e + 0] += qf * sv.x; acc[e + 1] += qf * sv.y;
            acc[e + 2] += qf * sv.z; acc[e + 3] += qf * sv.w;
        }
    }
    for (int j = 0; j <= i; ++j) {
        double s64 = 0.0;
#pragma unroll
        for (int f = 0; f < 16; ++f) s64 += qr[f] * ks[j][f];
        denom += s64;
        float s = (float)s64;
        const float4* vj = (const float4*)&vs[j][half];
#pragma unroll
        for (int e4 = 0; e4 < 8; ++e4) {
            float4 vv = vj[e4];
            acc[e4 * 4 + 0] += s * vv.x; acc[e4 * 4 + 1] += s * vv.y;
            acc[e4 * 4 + 2] += s * vv.z; acc[e4 * 4 + 3] += s * vv.w;
        }
    }

    const float z = (float)(1.0 / (denom + 1e-12));
    ushort* yp = &y3[(size_t)(n0 + i) * K3 + h * 64 + half];
#pragma unroll
    for (int e4 = 0; e4 < 8; ++e4) {
        ushort hs[4], ls[4];
#pragma unroll
        for (int j = 0; j < 4; ++j) {
            float val = acc[e4 * 4 + j] * z;
            ushort hh = bf_rne(val);
            hs[j] = hh;
            ls[j] = bf_rne(val - bf_to_f(hh));
        }
        ushort4 hv = make_ushort4(hs[0], hs[1], hs[2], hs[3]);
        *(ushort4*)(yp + e4 * 4)        = hv;   // hi
        *(ushort4*)(yp + 1024 + e4 * 4) = make_ushort4(ls[0], ls[1], ls[2], ls[3]); // lo
        *(ushort4*)(yp + 2048 + e4 * 4) = hv;   // hi copy
    }
}

extern "C" void kernel_launch(void* const* d_in, const int* in_sizes, int n_in,
                              void* d_out, int out_size, void* d_ws, size_t ws_size,
                              hipStream_t stream) {
    const float* X  = (const float*)d_in[0];
    const float* Wq = (const float*)d_in[1];
    const float* Wk = (const float*)d_in[2];
    const float* Wv = (const float*)d_in[3];
    const float* Wo = (const float*)d_in[4];
    float* out = (float*)d_out;

    double* q64   = (double*)d_ws;                 // 8 MB
    double* k64   = q64 + 1048576;                 // 8 MB
    float*  v     = (float*)(k64 + 1048576);       // 16 MB
    float*  KV    = v + 4194304;                   // 2 MB
    float*  KVpre = KV + 524288;                   // 2 MB
    double* Ksum  = (double*)(KVpre + 524288);     // 64 KB
    double* Kpre  = Ksum + 8192;                   // 64 KB
    ushort* X3    = (ushort*)(Kpre + 8192);        // 24 MB (reused as Y3)
    ushort* Wv3   = X3 + (size_t)4096 * K3;        // 6 MB
    ushort* Wo3   = Wv3 + (size_t)1024 * K3;       // 6 MB
    // total ~72.2 MB

    dim3 blk(256);
    split3<<<2048, blk, 0, stream>>>(X, X3, 4096, 1024, 2048);   // A-style [hi|lo|hi]
    split3<<<512, blk, 0, stream>>>(Wv, Wv3, 1024, 2048, 1024);  // B-style [hi|hi|lo]
    split3<<<512, blk, 0, stream>>>(Wo, Wo3, 1024, 2048, 1024);  // B-style [hi|hi|lo]
    gemm_qk_f64<<<dim3(8, 64), blk, 0, stream>>>(X, Wq, Wk, q64, k64);
    gemm_bf16x3<<<512, blk, 0, stream>>>(X3, Wv3, v, 1024);
    chunk_kv<<<dim3(NCH, NBH), blk, 0, stream>>>(k64, v, KV, Ksum);
    prefix_kv<<<dim3(NBH), blk, 0, stream>>>(KV, Ksum, KVpre, Kpre);
    attn_out<<<dim3(NCH, NBH), blk, 0, stream>>>(q64, k64, v, KVpre, Kpre, X3);
    gemm_bf16x3<<<512, blk, 0, stream>>>(X3, Wo3, out, 1024);
}